// Round 13
// baseline (622.100 us; speedup 1.0000x reference)
//
#include <hip/hip_runtime.h>

typedef unsigned short u16;
typedef unsigned int u32;
typedef __attribute__((ext_vector_type(8))) short sv8;   // 8 x bf16 (4 VGPR)
typedef __attribute__((ext_vector_type(4))) float fv4;   // MFMA accumulator

__device__ __forceinline__ u16 f2b(float f) {
  u32 u = __builtin_bit_cast(u32, f);
  u32 r = (u + 0x7fffu + ((u >> 16) & 1u)) >> 16;
  return (u16)r;
}
__device__ __forceinline__ float b2f(u16 h) {
  return __builtin_bit_cast(float, ((u32)h) << 16);
}
__device__ __forceinline__ void gld16(const void* g, void* l) {
  __builtin_amdgcn_global_load_lds(
      (const __attribute__((address_space(1))) u32*)g,
      (__attribute__((address_space(3))) u32*)l, 16, 0, 0);
}

// ---------------- cast f32 -> bf16 (both tensors, one launch) ----------------
__global__ __launch_bounds__(256) void cast2_k(const float4* __restrict__ inI,
                                               const float4* __restrict__ inT,
                                               u16* __restrict__ outI,
                                               u16* __restrict__ outT,
                                               int n4img, int n4tot) {
  int i = blockIdx.x * 256 + threadIdx.x;
  const int stride = gridDim.x * 256;
  for (; i < n4tot; i += stride) {
    const float4* in = (i < n4img) ? inI : inT;
    u16* out = (i < n4img) ? outI : outT;
    int k = (i < n4img) ? i : i - n4img;
    float4 v = in[k];
    u32 p0 = (u32)f2b(v.x) | ((u32)f2b(v.y) << 16);
    u32 p1 = (u32)f2b(v.z) | ((u32)f2b(v.w) << 16);
    uint2 o; o.x = p0; o.y = p1;
    ((uint2*)out)[k] = o;
  }
}

// ---------------- weight transpose + cast:  Wt[e][d] = W[d][e] ----------------
__global__ __launch_bounds__(256) void wtrans_k(const float* __restrict__ W0,
                                                const float* __restrict__ W1,
                                                const float* __restrict__ W2,
                                                const float* __restrict__ W3,
                                                u16* __restrict__ out) {
  const int z = blockIdx.z;
  const float* W = (z == 0) ? W0 : (z == 1) ? W1 : (z == 2) ? W2 : W3;
  u16* o = out + (size_t)z * 1048576;
  __shared__ float t[32][33];
  const int tid = threadIdx.x;
  const int r = tid >> 5, cc = tid & 31;
  const int d0 = blockIdx.x * 32, e0 = blockIdx.y * 32;
#pragma unroll
  for (int i = 0; i < 4; ++i)
    t[r + i * 8][cc] = W[(size_t)(d0 + r + i * 8) * 1024 + e0 + cc];
  __syncthreads();
#pragma unroll
  for (int i = 0; i < 4; ++i) {
    int row = r + i * 8;
    o[(size_t)(e0 + row) * 1024 + d0 + cc] = f2b(t[cc][row]);
  }
}

// ------ merged GEMM: 128x128, BK=64, 2-phase dbuf (R11 schedule), 512 thr ------
// R11 best: 135us/dispatch, 684 TF (2-phase structural ceiling). Untouched K-loop.
// NEW (MODE1): resid prefetched into 32 VGPR before the K-loop (nontemporal);
// first vmcnt(4) drains them once (~1 HBM latency), epilogue reads from regs.
template <int MODE>
__global__ __launch_bounds__(512, 4) void gemm2_k(
    const u16* __restrict__ Aimg, const u16* __restrict__ Atxt,
    const u16* __restrict__ Wimg, const u16* __restrict__ Wtxt,
    const float* __restrict__ bii, const float* __restrict__ btt,
    const float* __restrict__ rii, const float* __restrict__ rtt,
    u16* __restrict__ obi, u16* __restrict__ obt,
    float* __restrict__ ofi, float* __restrict__ oft) {
  __shared__ __attribute__((aligned(16))) char smem[65536];  // 2 x (A 16K | B 16K)
  const int tid = threadIdx.x;
  const int lane = tid & 63;
  const int w = tid >> 6;              // 0..7
  const int wm = w >> 2, wn = w & 3;   // 2 row-waves x 4 col-waves
  const int l15 = lane & 15, l4 = lane >> 4;
  const int lin = blockIdx.y * 8 + blockIdx.x;
  const int xcd = lin & 7, slot = lin >> 3;
  const int bcol0 = (slot & 7) * 128;
  const int prow = xcd + ((slot >> 3) << 3);     // 344 % 8 == 0 -> bijective

  const char* Ab; const char* Bb; const float* bias; const float* resid;
  u16* ob; float* of; int brow0;
  if (prow < 144) {
    brow0 = prow * 128;
    Ab = (const char*)Aimg + (size_t)brow0 * 2048;
    Bb = (const char*)Wimg + (size_t)bcol0 * 2048;
    bias = bii; resid = rii; ob = obi; of = ofi;
  } else {
    brow0 = (prow - 144) * 128;
    Ab = (const char*)Atxt + (size_t)brow0 * 2048;
    Bb = (const char*)Wtxt + (size_t)bcol0 * 2048;
    bias = btt; resid = rtt; ob = obt; of = oft;
  }
  const int wr = wm * 64;              // A rows for this wave
  const int wc = wn * 32;              // B rows (out cols) for this wave
  fv4 acc[4][2] = {};

  // MODE1: prefetch resid into regs (issued before all STAGE loads; drained by
  // the first vmcnt(4), i.e. during tile-0 compute; epilogue is then reg-only).
  float rv[4][4][2];
  if (MODE == 1) {
#pragma unroll
    for (int m = 0; m < 4; ++m)
#pragma unroll
      for (int j = 0; j < 4; ++j)
#pragma unroll
        for (int n = 0; n < 2; ++n) {
          const int row = brow0 + wr + m * 16 + l4 * 4 + j;
          const int col = bcol0 + wc + n * 16 + l15;
          rv[m][j][n] =
              __builtin_nontemporal_load(&resid[(size_t)row * 1024 + col]);
        }
  }

  const int srow = tid >> 3;           // 0..63
  const int schunk = tid & 7;          // 16B chunk in 128B row

  auto STAGE = [&](int bb, int k0) {
    char* base = smem + bb * 32768;
#pragma unroll
    for (int i = 0; i < 2; ++i) {
      int row = i * 64 + srow;
      int g = schunk ^ (row & 7);                          // source pre-swizzle
      gld16(Ab + (size_t)row * 2048 + k0 * 2 + g * 16,
            base + i * 8192 + tid * 16);                   // linear LDS dest
    }
#pragma unroll
    for (int i = 0; i < 2; ++i) {
      int row = i * 64 + srow;
      int g = schunk ^ (row & 7);
      gld16(Bb + (size_t)row * 2048 + k0 * 2 + g * 16,
            base + 16384 + i * 8192 + tid * 16);
    }
  };

  STAGE(0, 0);
  for (int t = 0; t < 16; ++t) {
    const int cur = t & 1;
    if (t < 15) {
      STAGE(cur ^ 1, (t + 1) * 64);
      asm volatile("s_waitcnt vmcnt(4)" ::: "memory");     // tile t landed
    } else {
      asm volatile("s_waitcnt vmcnt(0)" ::: "memory");
    }
    __builtin_amdgcn_s_barrier();
    __builtin_amdgcn_sched_barrier(0);
    const char* Al = smem + cur * 32768;
    const char* Bl = Al + 16384;
#pragma unroll
    for (int ks = 0; ks < 2; ++ks) {
      sv8 af[4], bf[2];
#pragma unroll
      for (int m = 0; m < 4; ++m) {
        int row = wr + m * 16 + l15;
        int c = (ks * 4 + l4) ^ (row & 7);                 // read-side swizzle
        af[m] = *(const sv8*)(Al + row * 128 + c * 16);
      }
#pragma unroll
      for (int n = 0; n < 2; ++n) {
        int row = wc + n * 16 + l15;
        int c = (ks * 4 + l4) ^ (row & 7);
        bf[n] = *(const sv8*)(Bl + row * 128 + c * 16);
      }
#pragma unroll
      for (int m = 0; m < 4; ++m)
#pragma unroll
        for (int n = 0; n < 2; ++n)
          acc[m][n] = __builtin_amdgcn_mfma_f32_16x16x32_bf16(af[m], bf[n], acc[m][n], 0, 0, 0);
    }
    __builtin_amdgcn_sched_barrier(0);
    __builtin_amdgcn_s_barrier();                          // buf[cur] fully read
  }

  float bv[2];
#pragma unroll
  for (int n = 0; n < 2; ++n) bv[n] = bias[bcol0 + wc + n * 16 + l15];
#pragma unroll
  for (int m = 0; m < 4; ++m) {
#pragma unroll
    for (int j = 0; j < 4; ++j) {
      const int row = brow0 + wr + m * 16 + l4 * 4 + j;
#pragma unroll
      for (int n = 0; n < 2; ++n) {                        // n innermost
        const int col = bcol0 + wc + n * 16 + l15;
        const size_t idx = (size_t)row * 1024 + col;
        float r = acc[m][n][j] + bv[n];
        if (MODE == 0) {
          ob[idx] = f2b(r);
        } else {
          __builtin_nontemporal_store(r + rv[m][j][n], &of[idx]);
        }
      }
    }
  }
}

// -------- fused attention: scores + masked softmax + P@E + gate --------
// One 512-thread block per b. Phase A: waves 4-7 score tile via global-frag
// MFMA, waves 0-3 row norms (R3-verified). Phase B: 8-lane-per-row parallel
// masked softmax -> P kept in LDS (no global round-trip). Phase C: PV+gate,
// 2 d-columns per thread (rep loop), P rows read as uniform ds_read_b128.
// Cross-block phase diversity lets score (MFMA/VMEM) and PV (VALU/LDS)
// co-schedule on a CU instead of running as serial dispatches.
__global__ __launch_bounds__(512, 2) void attn2_k(const u16* __restrict__ Xb,
                                                  const u16* __restrict__ Yb,
                                                  const u16* __restrict__ imgA,
                                                  const u16* __restrict__ txtA,
                                                  const void* __restrict__ xmask,
                                                  const void* __restrict__ ymask,
                                                  u16* __restrict__ gxw,
                                                  u16* __restrict__ gyw) {
  __shared__ float attL[48 * 65];        // stride 65 -> conflict-free col reads
  __shared__ float wxL[88];              // [0..35]=||x||, [36..85]=||y||
  __shared__ unsigned char msk[88];      // [0..35]=xm, [36..85]=ym
  __shared__ float P1L[36 * 64];         // normalized P1 rows (cols 0..49 valid)
  __shared__ float P2L[50 * 64];         // normalized P2 rows (cols 0..35 valid)
  const int b = blockIdx.x;
  const int tid = threadIdx.x;
  const int w = tid >> 6, lane = tid & 63;
  const int l15 = lane & 15, l4 = lane >> 4;

  // mask dtype auto-detect (int32 0/1 ORs to <=1; bytes OR to ~0x01010101)
  u32 det = 0;
  {
    const u32* mm = (const u32*)xmask;
#pragma unroll
    for (int i = 0; i < 16; ++i) det |= mm[i * 4];
    det |= mm[1] | mm[2] | mm[3];
  }
  const bool m_i32 = (det <= 1u);
  if (tid < 36)
    msk[tid] = (unsigned char)(m_i32 ? (((const int*)xmask)[b * 36 + tid] != 0)
                                     : (((const unsigned char*)xmask)[b * 36 + tid] != 0));
  if (tid >= 64 && tid < 114) {
    int m = tid - 64;
    msk[36 + m] = (unsigned char)(m_i32 ? (((const int*)ymask)[b * 50 + m] != 0)
                                        : (((const unsigned char*)ymask)[b * 50 + m] != 0));
  }

  const u16* Xr = Xb + (size_t)b * 36864;   // 36*1024
  const u16* Yr = Yb + (size_t)b * 51200;   // 50*1024

  // ---- phase A: norms (waves 0-3) + scores via global-frag MFMA (waves 4-7)
  if (w < 4) {
#pragma unroll
    for (int sweep = 0; sweep < 3; ++sweep) {
      int r = sweep * 32 + (tid >> 3);
      int j = tid & 7;
      if (r < 86) {
        const u32* p = (const u32*)((r < 36) ? (Xr + r * 1024)
                                             : (Yr + (size_t)(r - 36) * 1024)) + j * 64;
        float s = 0.f;
#pragma unroll
        for (int i = 0; i < 16; ++i) {
          uint4 q = ((const uint4*)p)[i];
          u32 qq[4] = {q.x, q.y, q.z, q.w};
#pragma unroll
          for (int k2 = 0; k2 < 4; ++k2) {
            float lo = __builtin_bit_cast(float, qq[k2] << 16);
            float hi = __builtin_bit_cast(float, qq[k2] & 0xffff0000u);
            s = fmaf(lo, lo, fmaf(hi, hi, s));
          }
        }
        s += __shfl_xor(s, 1); s += __shfl_xor(s, 2); s += __shfl_xor(s, 4);
        if (j == 0) wxL[r] = sqrtf(s);
      }
    }
  } else {
    const int tn = w - 4;
    fv4 ac0 = {}, ac1 = {}, ac2 = {};
    const u16* Yp = Yr + (size_t)(tn * 16 + l15) * 1024 + l4 * 8;
    const u16* Xp = Xr + (size_t)l15 * 1024 + l4 * 8;
#pragma unroll 2
    for (int ks = 0; ks < 32; ++ks) {
      sv8 bf = *(const sv8*)(Yp + ks * 32);
      sv8 a0 = *(const sv8*)(Xp + ks * 32);
      sv8 a1 = *(const sv8*)(Xp + 16 * 1024 + ks * 32);
      sv8 a2 = *(const sv8*)(Xp + 32 * 1024 + ks * 32);
      ac0 = __builtin_amdgcn_mfma_f32_16x16x32_bf16(a0, bf, ac0, 0, 0, 0);
      ac1 = __builtin_amdgcn_mfma_f32_16x16x32_bf16(a1, bf, ac1, 0, 0, 0);
      ac2 = __builtin_amdgcn_mfma_f32_16x16x32_bf16(a2, bf, ac2, 0, 0, 0);
    }
    const int col = tn * 16 + l15;
#pragma unroll
    for (int j = 0; j < 4; ++j) {
      attL[(l4 * 4 + j) * 65 + col] = ac0[j];
      attL[(16 + l4 * 4 + j) * 65 + col] = ac1[j];
      attL[(32 + l4 * 4 + j) * 65 + col] = ac2[j];
    }
  }
  __syncthreads();

  // ---- phase B: masked softmax (8 lanes per row), P -> LDS ----
#pragma unroll
  for (int sweep = 0; sweep < 2; ++sweep) {
    int R = sweep * 64 + (tid >> 3);
    int j = tid & 7;
    if (R < 36) {
      float wxn = wxL[R];
      float sv[7];
#pragma unroll
      for (int i = 0; i < 7; ++i) {
        int m = j + i * 8;
        if (m < 50) {
          float den = fmaxf(wxn * wxL[36 + m], 1e-8f);
          float v = attL[R * 65 + m] / den;
          sv[i] = msk[36 + m] ? -1e9f : v;
        } else sv[i] = -3.4e38f;
      }
      float mx = sv[0];
#pragma unroll
      for (int i = 1; i < 7; ++i) mx = fmaxf(mx, sv[i]);
      mx = fmaxf(mx, __shfl_xor(mx, 1));
      mx = fmaxf(mx, __shfl_xor(mx, 2));
      mx = fmaxf(mx, __shfl_xor(mx, 4));
      float e[7], sum = 0.f;
#pragma unroll
      for (int i = 0; i < 7; ++i) {
        e[i] = (j + i * 8 < 50) ? __expf(sv[i] - mx) : 0.f;
        sum += e[i];
      }
      sum += __shfl_xor(sum, 1); sum += __shfl_xor(sum, 2); sum += __shfl_xor(sum, 4);
      float rs = 1.f / sum;
#pragma unroll
      for (int i = 0; i < 7; ++i) {
        int m = j + i * 8;
        if (m < 50) P1L[R * 64 + m] = e[i] * rs;
      }
    } else if (R < 86) {
      int m = R - 36;
      float wym = wxL[R];
      float sv[5];
#pragma unroll
      for (int i = 0; i < 5; ++i) {
        int n = j + i * 8;
        if (n < 36) {
          float den = fmaxf(wxL[n] * wym, 1e-8f);
          float v = attL[n * 65 + m] / den;
          sv[i] = msk[n] ? -1e9f : v;
        } else sv[i] = -3.4e38f;
      }
      float mx = sv[0];
#pragma unroll
      for (int i = 1; i < 5; ++i) mx = fmaxf(mx, sv[i]);
      mx = fmaxf(mx, __shfl_xor(mx, 1));
      mx = fmaxf(mx, __shfl_xor(mx, 2));
      mx = fmaxf(mx, __shfl_xor(mx, 4));
      float e[5], sum = 0.f;
#pragma unroll
      for (int i = 0; i < 5; ++i) {
        e[i] = (j + i * 8 < 36) ? __expf(sv[i] - mx) : 0.f;
        sum += e[i];
      }
      sum += __shfl_xor(sum, 1); sum += __shfl_xor(sum, 2); sum += __shfl_xor(sum, 4);
      float rs = 1.f / sum;
#pragma unroll
      for (int i = 0; i < 5; ++i) {
        int n = j + i * 8;
        if (n < 36) P2L[m * 64 + n] = e[i] * rs;
      }
    }
  }
  __syncthreads();

  // ---- phase C: P @ E + gate, 2 d-columns per thread ----
#pragma unroll 1
  for (int rep = 0; rep < 2; ++rep) {
    const int d = rep * 512 + tid;
    const u16* tp = txtA + (size_t)b * 51200 + d;
    const u16* ip = imgA + (size_t)b * 36864 + d;
    float tv[50], iv[36];
#pragma unroll
    for (int m = 0; m < 50; ++m) tv[m] = b2f(tp[(size_t)m * 1024]);
#pragma unroll
    for (int n = 0; n < 36; ++n) iv[n] = b2f(ip[(size_t)n * 1024]);

    u16* gx = gxw + (size_t)b * 36864 + d;
#pragma unroll
    for (int n = 0; n < 36; ++n) {
      const float4* pr4 = (const float4*)(P1L + n * 64);
      float4 a4 = {0.f, 0.f, 0.f, 0.f};
#pragma unroll
      for (int i = 0; i < 12; ++i) {
        float4 p = pr4[i];
        a4.x = fmaf(p.x, tv[4 * i + 0], a4.x);
        a4.y = fmaf(p.y, tv[4 * i + 1], a4.y);
        a4.z = fmaf(p.z, tv[4 * i + 2], a4.z);
        a4.w = fmaf(p.w, tv[4 * i + 3], a4.w);
      }
      float acc = (a4.x + a4.y) + (a4.z + a4.w);
      acc = fmaf(P1L[n * 64 + 48], tv[48], acc);
      acc = fmaf(P1L[n * 64 + 49], tv[49], acc);
      float t = acc * iv[n];
      float g = acc / (1.f + __expf(-t));
      gx[(size_t)n * 1024] = f2b(g);
    }
    u16* gy = gyw + (size_t)b * 51200 + d;
#pragma unroll
    for (int m = 0; m < 50; ++m) {
      const float4* pr4 = (const float4*)(P2L + m * 64);
      float4 a4 = {0.f, 0.f, 0.f, 0.f};
#pragma unroll
      for (int i = 0; i < 9; ++i) {
        float4 p = pr4[i];
        a4.x = fmaf(p.x, iv[4 * i + 0], a4.x);
        a4.y = fmaf(p.y, iv[4 * i + 1], a4.y);
        a4.z = fmaf(p.z, iv[4 * i + 2], a4.z);
        a4.w = fmaf(p.w, iv[4 * i + 3], a4.w);
      }
      float acc = (a4.x + a4.y) + (a4.z + a4.w);
      float t = acc * tv[m];
      float g = acc / (1.f + __expf(-t));
      gy[(size_t)m * 1024] = f2b(g);
    }
  }
}

extern "C" void kernel_launch(void* const* d_in, const int* in_sizes, int n_in,
                              void* d_out, int out_size, void* d_ws, size_t ws_size,
                              hipStream_t stream) {
  (void)in_sizes; (void)n_in; (void)out_size; (void)ws_size;
  const float* imgE = (const float*)d_in[0];
  const float* txtE = (const float*)d_in[1];
  const void* xmask = d_in[2];
  const void* ymask = d_in[3];
  const float* W_img  = (const float*)d_in[4];
  const float* b_img  = (const float*)d_in[5];
  const float* W_txt  = (const float*)d_in[6];
  const float* b_txt  = (const float*)d_in[7];
  const float* W_img1 = (const float*)d_in[8];
  const float* b_img1 = (const float*)d_in[9];
  const float* W_txt1 = (const float*)d_in[10];
  const float* b_txt1 = (const float*)d_in[11];
  float* out_img = (float*)d_out;
  float* out_txt = out_img + (size_t)18874368;

  char* ws = (char*)d_ws;
  u16* Wt   = (u16*)(ws);                    // 4 x [1024][1024] bf16 (W^T)
  u16* imgA = (u16*)(ws + 8388608);          // [18432][1024] bf16
  u16* txtA = (u16*)(ws + 46137344);         // [25600][1024] bf16
  u16* Xb   = (u16*)(ws + 98566144);         // [18432][1024] bf16 (dies after attn2)
  u16* Yb   = (u16*)(ws + 136314880);        // [25600][1024] bf16 (dies after attn2)
  u16* gxw  = (u16*)(ws + 188743680);        // [18432][1024] bf16
  u16* gyw  = (u16*)(ws + 226492416);        // [25600][1024] bf16

  cast2_k<<<2048, 256, 0, stream>>>((const float4*)imgE, (const float4*)txtE,
                                    imgA, txtA, 4718592, 11272192);
  wtrans_k<<<dim3(32, 32, 4), 256, 0, stream>>>(W_img, W_txt, W_img1, W_txt1, Wt);
  gemm2_k<0><<<dim3(8, 344), 512, 0, stream>>>(
      imgA, txtA, Wt, Wt + 1048576, b_img, b_txt, nullptr, nullptr,
      Xb, Yb, nullptr, nullptr);
  attn2_k<<<512, 512, 0, stream>>>(Xb, Yb, imgA, txtA, xmask, ymask, gxw, gyw);
  gemm2_k<1><<<dim3(8, 344), 512, 0, stream>>>(
      gxw, gyw, Wt + 2097152, Wt + 3145728, b_img1, b_txt1, imgE, txtE,
      nullptr, nullptr, out_img, out_txt);
}

// Round 14
// 398.521 us; speedup vs baseline: 1.5610x; 1.5610x over previous
//
#include <hip/hip_runtime.h>

typedef unsigned short u16;
typedef unsigned int u32;
typedef __attribute__((ext_vector_type(8))) short sv8;   // 8 x bf16 (4 VGPR)
typedef __attribute__((ext_vector_type(4))) float fv4;   // MFMA accumulator

__device__ __forceinline__ u16 f2b(float f) {
  u32 u = __builtin_bit_cast(u32, f);
  u32 r = (u + 0x7fffu + ((u >> 16) & 1u)) >> 16;
  return (u16)r;
}
__device__ __forceinline__ float b2f(u16 h) {
  return __builtin_bit_cast(float, ((u32)h) << 16);
}
__device__ __forceinline__ void gld16(const void* g, void* l) {
  __builtin_amdgcn_global_load_lds(
      (const __attribute__((address_space(1))) u32*)g,
      (__attribute__((address_space(3))) u32*)l, 16, 0, 0);
}

// ---------------- cast f32 -> bf16 (both tensors, one launch) ----------------
__global__ __launch_bounds__(256) void cast2_k(const float4* __restrict__ inI,
                                               const float4* __restrict__ inT,
                                               u16* __restrict__ outI,
                                               u16* __restrict__ outT,
                                               int n4img, int n4tot) {
  int i = blockIdx.x * 256 + threadIdx.x;
  const int stride = gridDim.x * 256;
  for (; i < n4tot; i += stride) {
    const float4* in = (i < n4img) ? inI : inT;
    u16* out = (i < n4img) ? outI : outT;
    int k = (i < n4img) ? i : i - n4img;
    float4 v = in[k];
    u32 p0 = (u32)f2b(v.x) | ((u32)f2b(v.y) << 16);
    u32 p1 = (u32)f2b(v.z) | ((u32)f2b(v.w) << 16);
    uint2 o; o.x = p0; o.y = p1;
    ((uint2*)out)[k] = o;
  }
}

// ---------------- weight transpose + cast:  Wt[e][d] = W[d][e] ----------------
__global__ __launch_bounds__(256) void wtrans_k(const float* __restrict__ W0,
                                                const float* __restrict__ W1,
                                                const float* __restrict__ W2,
                                                const float* __restrict__ W3,
                                                u16* __restrict__ out) {
  const int z = blockIdx.z;
  const float* W = (z == 0) ? W0 : (z == 1) ? W1 : (z == 2) ? W2 : W3;
  u16* o = out + (size_t)z * 1048576;
  __shared__ float t[32][33];
  const int tid = threadIdx.x;
  const int r = tid >> 5, cc = tid & 31;
  const int d0 = blockIdx.x * 32, e0 = blockIdx.y * 32;
#pragma unroll
  for (int i = 0; i < 4; ++i)
    t[r + i * 8][cc] = W[(size_t)(d0 + r + i * 8) * 1024 + e0 + cc];
  __syncthreads();
#pragma unroll
  for (int i = 0; i < 4; ++i) {
    int row = r + i * 8;
    o[(size_t)(e0 + row) * 1024 + d0 + cc] = f2b(t[cc][row]);
  }
}

// ------ merged GEMM: 128x128, BK=64, 2-phase dbuf (R11 schedule), 512 thr ------
// R11 best: 135us/dispatch, 684 TF (2-phase structural ceiling). K-loop frozen.
// MODE1: resid prefetched into 32 VGPR before the K-loop (nontemporal); the
// first vmcnt(4) drains them during tile-0 compute; epilogue is reg-only.
// R13 lesson: do NOT fuse register-heavy phases onto this (spill signature:
// VGPR==cap + WRITE_SIZE excess).
template <int MODE>
__global__ __launch_bounds__(512, 4) void gemm2_k(
    const u16* __restrict__ Aimg, const u16* __restrict__ Atxt,
    const u16* __restrict__ Wimg, const u16* __restrict__ Wtxt,
    const float* __restrict__ bii, const float* __restrict__ btt,
    const float* __restrict__ rii, const float* __restrict__ rtt,
    u16* __restrict__ obi, u16* __restrict__ obt,
    float* __restrict__ ofi, float* __restrict__ oft) {
  __shared__ __attribute__((aligned(16))) char smem[65536];  // 2 x (A 16K | B 16K)
  const int tid = threadIdx.x;
  const int lane = tid & 63;
  const int w = tid >> 6;              // 0..7
  const int wm = w >> 2, wn = w & 3;   // 2 row-waves x 4 col-waves
  const int l15 = lane & 15, l4 = lane >> 4;
  const int lin = blockIdx.y * 8 + blockIdx.x;
  const int xcd = lin & 7, slot = lin >> 3;
  const int bcol0 = (slot & 7) * 128;
  const int prow = xcd + ((slot >> 3) << 3);     // 344 % 8 == 0 -> bijective

  const char* Ab; const char* Bb; const float* bias; const float* resid;
  u16* ob; float* of; int brow0;
  if (prow < 144) {
    brow0 = prow * 128;
    Ab = (const char*)Aimg + (size_t)brow0 * 2048;
    Bb = (const char*)Wimg + (size_t)bcol0 * 2048;
    bias = bii; resid = rii; ob = obi; of = ofi;
  } else {
    brow0 = (prow - 144) * 128;
    Ab = (const char*)Atxt + (size_t)brow0 * 2048;
    Bb = (const char*)Wtxt + (size_t)bcol0 * 2048;
    bias = btt; resid = rtt; ob = obt; of = oft;
  }
  const int wr = wm * 64;              // A rows for this wave
  const int wc = wn * 32;              // B rows (out cols) for this wave
  fv4 acc[4][2] = {};

  float rv[4][4][2];
  if (MODE == 1) {
#pragma unroll
    for (int m = 0; m < 4; ++m)
#pragma unroll
      for (int j = 0; j < 4; ++j)
#pragma unroll
        for (int n = 0; n < 2; ++n) {
          const int row = brow0 + wr + m * 16 + l4 * 4 + j;
          const int col = bcol0 + wc + n * 16 + l15;
          rv[m][j][n] =
              __builtin_nontemporal_load(&resid[(size_t)row * 1024 + col]);
        }
  }

  const int srow = tid >> 3;           // 0..63
  const int schunk = tid & 7;          // 16B chunk in 128B row

  auto STAGE = [&](int bb, int k0) {
    char* base = smem + bb * 32768;
#pragma unroll
    for (int i = 0; i < 2; ++i) {
      int row = i * 64 + srow;
      int g = schunk ^ (row & 7);                          // source pre-swizzle
      gld16(Ab + (size_t)row * 2048 + k0 * 2 + g * 16,
            base + i * 8192 + tid * 16);                   // linear LDS dest
    }
#pragma unroll
    for (int i = 0; i < 2; ++i) {
      int row = i * 64 + srow;
      int g = schunk ^ (row & 7);
      gld16(Bb + (size_t)row * 2048 + k0 * 2 + g * 16,
            base + 16384 + i * 8192 + tid * 16);
    }
  };

  STAGE(0, 0);
  for (int t = 0; t < 16; ++t) {
    const int cur = t & 1;
    if (t < 15) {
      STAGE(cur ^ 1, (t + 1) * 64);
      asm volatile("s_waitcnt vmcnt(4)" ::: "memory");     // tile t landed
    } else {
      asm volatile("s_waitcnt vmcnt(0)" ::: "memory");
    }
    __builtin_amdgcn_s_barrier();
    __builtin_amdgcn_sched_barrier(0);
    const char* Al = smem + cur * 32768;
    const char* Bl = Al + 16384;
#pragma unroll
    for (int ks = 0; ks < 2; ++ks) {
      sv8 af[4], bf[2];
#pragma unroll
      for (int m = 0; m < 4; ++m) {
        int row = wr + m * 16 + l15;
        int c = (ks * 4 + l4) ^ (row & 7);                 // read-side swizzle
        af[m] = *(const sv8*)(Al + row * 128 + c * 16);
      }
#pragma unroll
      for (int n = 0; n < 2; ++n) {
        int row = wc + n * 16 + l15;
        int c = (ks * 4 + l4) ^ (row & 7);
        bf[n] = *(const sv8*)(Bl + row * 128 + c * 16);
      }
#pragma unroll
      for (int m = 0; m < 4; ++m)
#pragma unroll
        for (int n = 0; n < 2; ++n)
          acc[m][n] = __builtin_amdgcn_mfma_f32_16x16x32_bf16(af[m], bf[n], acc[m][n], 0, 0, 0);
    }
    __builtin_amdgcn_sched_barrier(0);
    __builtin_amdgcn_s_barrier();                          // buf[cur] fully read
  }

  float bv[2];
#pragma unroll
  for (int n = 0; n < 2; ++n) bv[n] = bias[bcol0 + wc + n * 16 + l15];
#pragma unroll
  for (int m = 0; m < 4; ++m) {
#pragma unroll
    for (int j = 0; j < 4; ++j) {
      const int row = brow0 + wr + m * 16 + l4 * 4 + j;
#pragma unroll
      for (int n = 0; n < 2; ++n) {                        // n innermost
        const int col = bcol0 + wc + n * 16 + l15;
        const size_t idx = (size_t)row * 1024 + col;
        float r = acc[m][n][j] + bv[n];
        if (MODE == 0) {
          ob[idx] = f2b(r);
        } else {
          __builtin_nontemporal_store(r + rv[m][j][n], &of[idx]);
        }
      }
    }
  }
}

// ---------------- scores + masked softmax (one block per b) ----------------
__global__ __launch_bounds__(512) void score_k(const u16* __restrict__ Xb,
                                               const u16* __restrict__ Yb,
                                               const void* __restrict__ xmask,
                                               const void* __restrict__ ymask,
                                               float* __restrict__ P1g,
                                               float* __restrict__ P2g) {
  __shared__ float attL[48 * 65];        // stride 65 -> conflict-free col reads
  __shared__ float wxL[88];              // [0..35]=||x||, [36..85]=||y||
  __shared__ unsigned char msk[88];      // [0..35]=xm, [36..85]=ym
  const int b = blockIdx.x;
  const int tid = threadIdx.x;
  const int w = tid >> 6, lane = tid & 63;
  const int l15 = lane & 15, l4 = lane >> 4;

  // mask dtype auto-detect (int32 0/1 ORs to <=1; bytes OR to ~0x01010101)
  u32 det = 0;
  {
    const u32* mm = (const u32*)xmask;
#pragma unroll
    for (int i = 0; i < 16; ++i) det |= mm[i * 4];
    det |= mm[1] | mm[2] | mm[3];
  }
  const bool m_i32 = (det <= 1u);
  if (tid < 36)
    msk[tid] = (unsigned char)(m_i32 ? (((const int*)xmask)[b * 36 + tid] != 0)
                                     : (((const unsigned char*)xmask)[b * 36 + tid] != 0));
  if (tid >= 64 && tid < 114) {
    int m = tid - 64;
    msk[36 + m] = (unsigned char)(m_i32 ? (((const int*)ymask)[b * 50 + m] != 0)
                                        : (((const unsigned char*)ymask)[b * 50 + m] != 0));
  }

  const u16* Xr = Xb + (size_t)b * 36864;   // 36*1024
  const u16* Yr = Yb + (size_t)b * 51200;   // 50*1024

  if (w < 4) {
#pragma unroll
    for (int sweep = 0; sweep < 3; ++sweep) {
      int r = sweep * 32 + (tid >> 3);
      int j = tid & 7;
      if (r < 86) {
        const u32* p = (const u32*)((r < 36) ? (Xr + r * 1024)
                                             : (Yr + (size_t)(r - 36) * 1024)) + j * 64;
        float s = 0.f;
#pragma unroll
        for (int i = 0; i < 16; ++i) {
          uint4 q = ((const uint4*)p)[i];
          u32 qq[4] = {q.x, q.y, q.z, q.w};
#pragma unroll
          for (int k2 = 0; k2 < 4; ++k2) {
            float lo = __builtin_bit_cast(float, qq[k2] << 16);
            float hi = __builtin_bit_cast(float, qq[k2] & 0xffff0000u);
            s = fmaf(lo, lo, fmaf(hi, hi, s));
          }
        }
        s += __shfl_xor(s, 1); s += __shfl_xor(s, 2); s += __shfl_xor(s, 4);
        if (j == 0) wxL[r] = sqrtf(s);
      }
    }
  } else {
    const int tn = w - 4;
    fv4 ac0 = {}, ac1 = {}, ac2 = {};
    const u16* Yp = Yr + (size_t)(tn * 16 + l15) * 1024 + l4 * 8;
    const u16* Xp = Xr + (size_t)l15 * 1024 + l4 * 8;
#pragma unroll 2
    for (int ks = 0; ks < 32; ++ks) {
      sv8 bf = *(const sv8*)(Yp + ks * 32);
      sv8 a0 = *(const sv8*)(Xp + ks * 32);
      sv8 a1 = *(const sv8*)(Xp + 16 * 1024 + ks * 32);
      sv8 a2 = *(const sv8*)(Xp + 32 * 1024 + ks * 32);
      ac0 = __builtin_amdgcn_mfma_f32_16x16x32_bf16(a0, bf, ac0, 0, 0, 0);
      ac1 = __builtin_amdgcn_mfma_f32_16x16x32_bf16(a1, bf, ac1, 0, 0, 0);
      ac2 = __builtin_amdgcn_mfma_f32_16x16x32_bf16(a2, bf, ac2, 0, 0, 0);
    }
    const int col = tn * 16 + l15;
#pragma unroll
    for (int j = 0; j < 4; ++j) {
      attL[(l4 * 4 + j) * 65 + col] = ac0[j];
      attL[(16 + l4 * 4 + j) * 65 + col] = ac1[j];
      attL[(32 + l4 * 4 + j) * 65 + col] = ac2[j];
    }
  }
  __syncthreads();

#pragma unroll
  for (int sweep = 0; sweep < 2; ++sweep) {
    int R = sweep * 64 + (tid >> 3);
    int j = tid & 7;
    if (R < 36) {
      float wxn = wxL[R];
      float sv[7];
#pragma unroll
      for (int i = 0; i < 7; ++i) {
        int m = j + i * 8;
        if (m < 50) {
          float den = fmaxf(wxn * wxL[36 + m], 1e-8f);
          float v = attL[R * 65 + m] / den;
          sv[i] = msk[36 + m] ? -1e9f : v;
        } else sv[i] = -3.4e38f;
      }
      float mx = sv[0];
#pragma unroll
      for (int i = 1; i < 7; ++i) mx = fmaxf(mx, sv[i]);
      mx = fmaxf(mx, __shfl_xor(mx, 1));
      mx = fmaxf(mx, __shfl_xor(mx, 2));
      mx = fmaxf(mx, __shfl_xor(mx, 4));
      float e[7], sum = 0.f;
#pragma unroll
      for (int i = 0; i < 7; ++i) {
        e[i] = (j + i * 8 < 50) ? __expf(sv[i] - mx) : 0.f;
        sum += e[i];
      }
      sum += __shfl_xor(sum, 1); sum += __shfl_xor(sum, 2); sum += __shfl_xor(sum, 4);
      float rs = 1.f / sum;
      float* dst = P1g + ((size_t)b * 36 + R) * 64;
#pragma unroll
      for (int i = 0; i < 7; ++i) {
        int m = j + i * 8;
        if (m < 50) dst[m] = e[i] * rs;
      }
    } else if (R < 86) {
      int m = R - 36;
      float wym = wxL[R];
      float sv[5];
#pragma unroll
      for (int i = 0; i < 5; ++i) {
        int n = j + i * 8;
        if (n < 36) {
          float den = fmaxf(wxL[n] * wym, 1e-8f);
          float v = attL[n * 65 + m] / den;
          sv[i] = msk[n] ? -1e9f : v;
        } else sv[i] = -3.4e38f;
      }
      float mx = sv[0];
#pragma unroll
      for (int i = 1; i < 5; ++i) mx = fmaxf(mx, sv[i]);
      mx = fmaxf(mx, __shfl_xor(mx, 1));
      mx = fmaxf(mx, __shfl_xor(mx, 2));
      mx = fmaxf(mx, __shfl_xor(mx, 4));
      float e[5], sum = 0.f;
#pragma unroll
      for (int i = 0; i < 5; ++i) {
        e[i] = (j + i * 8 < 36) ? __expf(sv[i] - mx) : 0.f;
        sum += e[i];
      }
      sum += __shfl_xor(sum, 1); sum += __shfl_xor(sum, 2); sum += __shfl_xor(sum, 4);
      float rs = 1.f / sum;
      float* dst = P2g + ((size_t)b * 50 + m) * 64;
#pragma unroll
      for (int i = 0; i < 5; ++i) {
        int n = j + i * 8;
        if (n < 36) dst[n] = e[i] * rs;
      }
    }
  }
}

// ---------------- P @ E + gate (thread = one d-column of one b) ----------------
__global__ __launch_bounds__(256) void pv_k(const float* __restrict__ P1g,
                                            const float* __restrict__ P2g,
                                            const u16* __restrict__ imgA,
                                            const u16* __restrict__ txtA,
                                            u16* __restrict__ gxw,
                                            u16* __restrict__ gyw) {
  __shared__ float ldsP1[36 * 64];
  __shared__ float ldsP2[50 * 64];
  const int b = blockIdx.x & 511;
  const int d = ((blockIdx.x >> 9) << 8) + threadIdx.x;
  const int tid = threadIdx.x;

  {
    const float4* s1 = (const float4*)(P1g + (size_t)b * 2304);
    float4* l1 = (float4*)ldsP1;
    for (int i = tid; i < 576; i += 256) l1[i] = s1[i];
    const float4* s2 = (const float4*)(P2g + (size_t)b * 3200);
    float4* l2 = (float4*)ldsP2;
    for (int i = tid; i < 800; i += 256) l2[i] = s2[i];
  }

  const u16* tp = txtA + (size_t)b * 51200 + d;
  const u16* ip = imgA + (size_t)b * 36864 + d;
  float tv[50], iv[36];
#pragma unroll
  for (int m = 0; m < 50; ++m) tv[m] = b2f(tp[(size_t)m * 1024]);
#pragma unroll
  for (int n = 0; n < 36; ++n) iv[n] = b2f(ip[(size_t)n * 1024]);
  __syncthreads();

  u16* gx = gxw + (size_t)b * 36864 + d;
#pragma unroll
  for (int n = 0; n < 36; ++n) {
    const float4* pr4 = (const float4*)(ldsP1 + n * 64);
    float4 a4 = {0.f, 0.f, 0.f, 0.f};
#pragma unroll
    for (int i = 0; i < 12; ++i) {
      float4 p = pr4[i];
      a4.x = fmaf(p.x, tv[4 * i + 0], a4.x);
      a4.y = fmaf(p.y, tv[4 * i + 1], a4.y);
      a4.z = fmaf(p.z, tv[4 * i + 2], a4.z);
      a4.w = fmaf(p.w, tv[4 * i + 3], a4.w);
    }
    float acc = (a4.x + a4.y) + (a4.z + a4.w);
    acc = fmaf(ldsP1[n * 64 + 48], tv[48], acc);
    acc = fmaf(ldsP1[n * 64 + 49], tv[49], acc);
    float t = acc * iv[n];
    float g = acc / (1.f + __expf(-t));
    gx[(size_t)n * 1024] = f2b(g);
  }
  u16* gy = gyw + (size_t)b * 51200 + d;
#pragma unroll
  for (int m = 0; m < 50; ++m) {
    const float4* pr4 = (const float4*)(ldsP2 + m * 64);
    float4 a4 = {0.f, 0.f, 0.f, 0.f};
#pragma unroll
    for (int i = 0; i < 9; ++i) {
      float4 p = pr4[i];
      a4.x = fmaf(p.x, iv[4 * i + 0], a4.x);
      a4.y = fmaf(p.y, iv[4 * i + 1], a4.y);
      a4.z = fmaf(p.z, iv[4 * i + 2], a4.z);
      a4.w = fmaf(p.w, iv[4 * i + 3], a4.w);
    }
    float acc = (a4.x + a4.y) + (a4.z + a4.w);
    float t = acc * tv[m];
    float g = acc / (1.f + __expf(-t));
    gy[(size_t)m * 1024] = f2b(g);
  }
}

extern "C" void kernel_launch(void* const* d_in, const int* in_sizes, int n_in,
                              void* d_out, int out_size, void* d_ws, size_t ws_size,
                              hipStream_t stream) {
  (void)in_sizes; (void)n_in; (void)out_size; (void)ws_size;
  const float* imgE = (const float*)d_in[0];
  const float* txtE = (const float*)d_in[1];
  const void* xmask = d_in[2];
  const void* ymask = d_in[3];
  const float* W_img  = (const float*)d_in[4];
  const float* b_img  = (const float*)d_in[5];
  const float* W_txt  = (const float*)d_in[6];
  const float* b_txt  = (const float*)d_in[7];
  const float* W_img1 = (const float*)d_in[8];
  const float* b_img1 = (const float*)d_in[9];
  const float* W_txt1 = (const float*)d_in[10];
  const float* b_txt1 = (const float*)d_in[11];
  float* out_img = (float*)d_out;
  float* out_txt = out_img + (size_t)18874368;

  char* ws = (char*)d_ws;
  u16* Wt   = (u16*)(ws);                    // 4 x [1024][1024] bf16 (W^T)
  u16* imgA = (u16*)(ws + 8388608);          // [18432][1024] bf16
  u16* txtA = (u16*)(ws + 46137344);         // [25600][1024] bf16
  u16* Xb   = (u16*)(ws + 98566144);         // [18432][1024] bf16 (dies after score_k)
  u16* Yb   = (u16*)(ws + 136314880);        // [25600][1024] bf16 (dies after score_k)
  float* P1g = (float*)(ws + 188743680);     // [512][36][64] f32
  float* P2g = (float*)(ws + 193462272);     // [512][50][64] f32
  u16* gxw  = (u16*)(ws + 98566144);         // reuses Xb slot
  u16* gyw  = (u16*)(ws + 136314880);        // reuses Yb slot

  cast2_k<<<2048, 256, 0, stream>>>((const float4*)imgE, (const float4*)txtE,
                                    imgA, txtA, 4718592, 11272192);
  wtrans_k<<<dim3(32, 32, 4), 256, 0, stream>>>(W_img, W_txt, W_img1, W_txt1, Wt);
  gemm2_k<0><<<dim3(8, 344), 512, 0, stream>>>(
      imgA, txtA, Wt, Wt + 1048576, b_img, b_txt, nullptr, nullptr,
      Xb, Yb, nullptr, nullptr);
  score_k<<<512, 512, 0, stream>>>(Xb, Yb, xmask, ymask, P1g, P2g);
  pv_k<<<2048, 256, 0, stream>>>(P1g, P2g, imgA, txtA, gxw, gyw);
  gemm2_k<1><<<dim3(8, 344), 512, 0, stream>>>(
      gxw, gyw, Wt + 2097152, Wt + 3145728, b_img1, b_txt1, imgE, txtE,
      nullptr, nullptr, out_img, out_txt);
}